// Round 3
// baseline (8305.145 us; speedup 1.0000x reference)
//
#include <hip/hip_runtime.h>
#include <hip/hip_bf16.h>

// VanillaRNN: S=512,B=256,E=256,H=1024,C=10, vocab=10
// R3: replace 16-way serialized atomic-RMW flag with per-wg release-store
//     flag slots (monotonic step counters); vectorize state stores via
//     per-wave LDS transpose -> 16B nontemporal stores.

typedef __attribute__((ext_vector_type(8))) short short8;
typedef __attribute__((ext_vector_type(4))) float f32x4;

#define S_LEN 512
#define HDIM  1024
#define NVOC  10

// ws layout (bytes)
#define OFF_WF    0u          // 1024*1024 bf16 frag-packed = 2 MB
#define OFF_PROJ  2097152u    // 10*1024 f32
#define OFF_STBF  2138112u    // 2 x 256*1024 bf16 (ping-pong)
#define OFF_STF   3186688u    // 256*1024 f32
#define OFF_FLAGS 4235264u    // 16 groups * 16 wgs u32 (monotonic)

__global__ void zero_flags_k(unsigned int* flags) {
    int id = threadIdx.x;
    if (id < 256) flags[id] = 0u;
}

// proj[v][h] = sum_e emb[v][e]*W_hx[e][h] + b_h[h]
__global__ void proj_k(const float* __restrict__ emb, const float* __restrict__ W_hx,
                       const float* __restrict__ b_h, float* __restrict__ proj) {
    int id = blockIdx.x * 256 + threadIdx.x;
    if (id >= NVOC * HDIM) return;
    int v = id >> 10, h = id & 1023;
    float a = b_h[h];
    #pragma unroll 8
    for (int e = 0; e < 256; ++e) a += emb[v * 256 + e] * W_hx[e * HDIM + h];
    proj[id] = a;
}

static __device__ inline unsigned short f2bf(float f) {
    unsigned u = __builtin_bit_cast(unsigned, f);
    return (unsigned short)((u + 0x7fffu + ((u >> 16) & 1u)) >> 16);
}

// pack W_hh[k][n] (f32) -> Wf frag layout: [nt(64)][kk(32)][lane(64)][8] bf16
__global__ void packw_k(const float* __restrict__ W_hh, unsigned short* __restrict__ Wf) {
    int idx = blockIdx.x * 256 + threadIdx.x;   // 131072 total
    int lane = idx & 63, kk = (idx >> 6) & 31, nt = idx >> 11;
    int k0 = kk * 32 + (lane >> 4) * 8;
    int col = nt * 16 + (lane & 15);
    short8 v;
    #pragma unroll
    for (int j = 0; j < 8; ++j) v[j] = (short)f2bf(W_hh[(k0 + j) * HDIM + col]);
    *(short8*)(Wf + (size_t)idx * 8) = v;
}

__global__ __launch_bounds__(256, 1) void rnn_steps_k(
    const int* __restrict__ x, const unsigned short* __restrict__ Wf,
    const float* __restrict__ proj, unsigned short* __restrict__ stbf,
    float* __restrict__ stf, unsigned int* __restrict__ flags)
{
    const int bid = blockIdx.x;
    // group g's 16 wgs all land on XCD g>>1 under bid%8 round-robin
    const int g   = ((bid & 7) << 1) | ((bid >> 3) & 1);   // 0..15 batch-group
    const int wgn = bid >> 4;                              // 0..15 col-block
    const int tid = threadIdx.x;
    const int wave = tid >> 6, lane = tid & 63;
    const int b0 = g << 4;
    const int nt = (wgn << 2) + wave;      // global 16-col tile index
    const int n0 = nt << 4;                // col base (per wave)
    const int wg_n0 = wgn << 6;            // col base (per workgroup)
    const int row = lane & 15;
    const int kl  = lane >> 4;

    __shared__ __align__(16) char Abuf[32768];     // 16 x 1024 bf16 (swizzled)
    __shared__ __align__(16) char Tbuf[4 * 768];   // per-wave 16x16 transpose, stride 48
    __shared__ unsigned char xl[S_LEN * 16];
    __shared__ float pl[NVOC * 64];

    for (int i = tid; i < S_LEN * 16; i += 256)
        xl[i] = (unsigned char)x[((i >> 4) << 8) + b0 + (i & 15)];
    for (int i = tid; i < NVOC * 64; i += 256)
        pl[i] = proj[(i >> 6) * HDIM + wg_n0 + (i & 63)];

    // B fragments: wave's K=1024 x 16-col slice of W_hh, in VGPRs/AGPRs
    short8 bfr[32];
    const short8* wp = (const short8*)Wf;
    #pragma unroll
    for (int kk = 0; kk < 32; ++kk)
        bfr[kk] = wp[((nt << 5) + kk) * 64 + lane];

    __syncthreads();

    const int sw = (row & 7) << 4;   // XOR swizzle
    const int abase = row << 11;
    const int klb = kl << 4;
    unsigned int* myflag = flags + (g << 4) + wgn;

    for (int s = 0; s < S_LEN; ++s) {
        f32x4 acc0 = {0.f, 0.f, 0.f, 0.f};
        f32x4 acc1 = acc0, acc2 = acc0, acc3 = acc0;
        if (s > 0) {
            // wait: all 16 wgs of this group finished step s-1 (flag >= s)
            if (tid < 16) {
                const unsigned int* fp = flags + (g << 4) + tid;
                while (__hip_atomic_load(fp, __ATOMIC_RELAXED, __HIP_MEMORY_SCOPE_AGENT) < (unsigned)s) {}
            }
            __syncthreads();
            __builtin_amdgcn_fence(__ATOMIC_ACQUIRE, "agent");
            // stage prev state tile (16 rows x 2048 B), pre-swizzled source
            const char* src = (const char*)stbf + (((s - 1) & 1) << 19) + (g << 15);
            #pragma unroll
            for (int it = 0; it < 8; ++it) {
                int o = (it * 256 + tid) * 16;
                int arow = o >> 11;
                int soff = (arow << 11) + ((o & 2047) ^ ((arow & 7) << 4));
                __builtin_amdgcn_global_load_lds(
                    (const __attribute__((address_space(1))) void*)(src + soff),
                    (__attribute__((address_space(3))) void*)(Abuf + it * 4096 + wave * 1024),
                    16, 0, 0);
            }
            __syncthreads();
            #pragma unroll
            for (int kk = 0; kk < 32; kk += 4) {
                short8 a0 = *(const short8*)(Abuf + abase + ((((kk + 0) << 6) + klb) ^ sw));
                short8 a1 = *(const short8*)(Abuf + abase + ((((kk + 1) << 6) + klb) ^ sw));
                short8 a2 = *(const short8*)(Abuf + abase + ((((kk + 2) << 6) + klb) ^ sw));
                short8 a3 = *(const short8*)(Abuf + abase + ((((kk + 3) << 6) + klb) ^ sw));
                acc0 = __builtin_amdgcn_mfma_f32_16x16x32_bf16(a0, bfr[kk + 0], acc0, 0, 0, 0);
                acc1 = __builtin_amdgcn_mfma_f32_16x16x32_bf16(a1, bfr[kk + 1], acc1, 0, 0, 0);
                acc2 = __builtin_amdgcn_mfma_f32_16x16x32_bf16(a2, bfr[kk + 2], acc2, 0, 0, 0);
                acc3 = __builtin_amdgcn_mfma_f32_16x16x32_bf16(a3, bfr[kk + 3], acc3, 0, 0, 0);
            }
        }
        f32x4 accs = acc0 + acc1 + acc2 + acc3;

        if (s < S_LEN - 1) {
            // tanh + per-wave 16x16 LDS transpose (row stride 48 B)
            char* tb = Tbuf + wave * 768;
            #pragma unroll
            for (int j = 0; j < 4; ++j) {
                int r = (kl << 2) + j;
                int xv = xl[(s << 4) + r];
                float z = accs[j] + pl[(xv << 6) + (wave << 4) + row];
                z = fminf(15.f, fmaxf(-15.f, z));
                float e = exp2f(z * 2.885390082f);
                *(unsigned short*)(tb + r * 48 + (row << 1)) = f2bf((e - 1.f) / (e + 1.f));
            }
            asm volatile("s_waitcnt lgkmcnt(0)" ::: "memory");
            __builtin_amdgcn_sched_barrier(0);
            if (lane < 32) {
                int r = lane >> 1, half = lane & 1;
                short8 v = *(const short8*)(tb + r * 48 + (half << 4));
                __builtin_nontemporal_store(v,
                    (short8*)(stbf + ((s & 1) << 18) + ((b0 + r) << 10) + n0 + (half << 3)));
            }
            __syncthreads();  // drain all waves' stores (vmcnt0) before flag
            if (tid == 0)
                __hip_atomic_store(myflag, (unsigned)(s + 1),
                                   __ATOMIC_RELEASE, __HIP_MEMORY_SCOPE_AGENT);
        } else {
            // final step: f32 state for output projection
            #pragma unroll
            for (int j = 0; j < 4; ++j) {
                int r = (kl << 2) + j;
                int xv = xl[(s << 4) + r];
                float z = accs[j] + pl[(xv << 6) + (wave << 4) + row];
                z = fminf(15.f, fmaxf(-15.f, z));
                float e = exp2f(z * 2.885390082f);
                stf[((b0 + r) << 10) + n0 + row] = (e - 1.f) / (e + 1.f);
            }
        }
    }
}

// out[b][c] = state_f32[b] @ W_ph[:,c] + b_p[c]
__global__ void outproj_k(const float* __restrict__ stf, const float* __restrict__ W_ph,
                          const float* __restrict__ b_p, float* __restrict__ out) {
    int b = blockIdx.x, t = threadIdx.x;
    float acc[10];
    #pragma unroll
    for (int c = 0; c < 10; ++c) acc[c] = 0.f;
    for (int h = t; h < HDIM; h += 256) {
        float sv = stf[b * HDIM + h];
        const float* w = W_ph + h * 10;
        #pragma unroll
        for (int c = 0; c < 10; ++c) acc[c] += sv * w[c];
    }
    __shared__ float red[256][10];
    #pragma unroll
    for (int c = 0; c < 10; ++c) red[t][c] = acc[c];
    __syncthreads();
    for (int off = 128; off > 0; off >>= 1) {
        if (t < off) {
            #pragma unroll
            for (int c = 0; c < 10; ++c) red[t][c] += red[t + off][c];
        }
        __syncthreads();
    }
    if (t < 10) out[b * 10 + t] = red[0][t] + b_p[t];
}

extern "C" void kernel_launch(void* const* d_in, const int* in_sizes, int n_in,
                              void* d_out, int out_size, void* d_ws, size_t ws_size,
                              hipStream_t stream) {
    const int*   x    = (const int*)d_in[0];
    const float* emb  = (const float*)d_in[1];
    const float* W_hx = (const float*)d_in[2];
    const float* W_hh = (const float*)d_in[3];
    const float* W_ph = (const float*)d_in[4];
    const float* b_h  = (const float*)d_in[5];
    const float* b_p  = (const float*)d_in[6];

    char* ws = (char*)d_ws;
    unsigned short* Wf    = (unsigned short*)(ws + OFF_WF);
    float*          proj  = (float*)(ws + OFF_PROJ);
    unsigned short* stbf  = (unsigned short*)(ws + OFF_STBF);
    float*          stf   = (float*)(ws + OFF_STF);
    unsigned int*   flags = (unsigned int*)(ws + OFF_FLAGS);

    zero_flags_k<<<1, 256, 0, stream>>>(flags);
    proj_k<<<40, 256, 0, stream>>>(emb, W_hx, b_h, proj);
    packw_k<<<512, 256, 0, stream>>>(W_hh, Wf);
    rnn_steps_k<<<256, 256, 0, stream>>>(x, Wf, proj, stbf, stf, flags);
    outproj_k<<<256, 256, 0, stream>>>(stf, W_ph, b_p, (float*)d_out);
}

// Round 4
// 5743.286 us; speedup vs baseline: 1.4461x; 1.4461x over previous
//
#include <hip/hip_runtime.h>
#include <hip/hip_bf16.h>

// VanillaRNN: S=512,B=256,E=256,H=1024,C=10, vocab=10
// R4: revert to round-2 protocol (RMW counter flag, acquire poll, scalar
//     stores). ONE change: group = 4 wgs x 1024 threads (was 16 x 256)
//     -> 4 serialized RMWs instead of 16, 4x fewer 32KB tile re-reads.

typedef __attribute__((ext_vector_type(8))) short short8;
typedef __attribute__((ext_vector_type(4))) float f32x4;

#define S_LEN 512
#define HDIM  1024
#define NVOC  10

// ws layout (bytes)
#define OFF_WF    0u          // 1024*1024 bf16 frag-packed = 2 MB
#define OFF_PROJ  2097152u    // 10*1024 f32
#define OFF_STBF  2138112u    // 2 x 256*1024 bf16 (ping-pong)
#define OFF_STF   3186688u    // 256*1024 f32
#define OFF_FLAGS 4235264u    // 16 groups u32 (monotonic counters)

__global__ void zero_flags_k(unsigned int* flags) {
    int id = threadIdx.x;
    if (id < 16) flags[id] = 0u;
}

// proj[v][h] = sum_e emb[v][e]*W_hx[e][h] + b_h[h]
__global__ void proj_k(const float* __restrict__ emb, const float* __restrict__ W_hx,
                       const float* __restrict__ b_h, float* __restrict__ proj) {
    int id = blockIdx.x * 256 + threadIdx.x;
    if (id >= NVOC * HDIM) return;
    int v = id >> 10, h = id & 1023;
    float a = b_h[h];
    #pragma unroll 8
    for (int e = 0; e < 256; ++e) a += emb[v * 256 + e] * W_hx[e * HDIM + h];
    proj[id] = a;
}

static __device__ inline unsigned short f2bf(float f) {
    unsigned u = __builtin_bit_cast(unsigned, f);
    return (unsigned short)((u + 0x7fffu + ((u >> 16) & 1u)) >> 16);
}

// pack W_hh[k][n] (f32) -> Wf frag layout: [nt(64)][kk(32)][lane(64)][8] bf16
// lane l of (nt,kk) holds W[kk*32 + (l>>4)*8 + j][nt*16 + (l&15)]
__global__ void packw_k(const float* __restrict__ W_hh, unsigned short* __restrict__ Wf) {
    int idx = blockIdx.x * 256 + threadIdx.x;   // 131072 total
    int lane = idx & 63, kk = (idx >> 6) & 31, nt = idx >> 11;
    int k0 = kk * 32 + (lane >> 4) * 8;
    int col = nt * 16 + (lane & 15);
    short8 v;
    #pragma unroll
    for (int j = 0; j < 8; ++j) v[j] = (short)f2bf(W_hh[(k0 + j) * HDIM + col]);
    *(short8*)(Wf + (size_t)idx * 8) = v;
}

__global__ __launch_bounds__(1024, 1) void rnn_steps_k(
    const int* __restrict__ x, const unsigned short* __restrict__ Wf,
    const float* __restrict__ proj, unsigned short* __restrict__ stbf,
    float* __restrict__ stf, unsigned int* __restrict__ flags)
{
    const int bid = blockIdx.x;            // 64 wgs
    const int g   = bid & 15;              // group: bids g,g+16,g+32,g+48 share XCD g%8
    const int wgn = bid >> 4;              // 0..3 col-block (256 cols each)
    const int tid = threadIdx.x;
    const int wave = tid >> 6, lane = tid & 63;
    const int b0 = g << 4;                 // batch row base
    const int nt = (wgn << 4) + wave;      // global 16-col tile index (0..63)
    const int n0 = nt << 4;                // col base (per wave)
    const int wg_n0 = wgn << 8;            // col base (per workgroup)
    const int row = lane & 15;
    const int kl  = lane >> 4;

    __shared__ __align__(16) char Abuf[32768];     // 16 x 1024 bf16 (swizzled)
    __shared__ unsigned char xl[S_LEN * 16];       // x slice for this group
    __shared__ float pl[NVOC * 256];               // proj slice for this wg

    for (int i = tid; i < S_LEN * 16; i += 1024)
        xl[i] = (unsigned char)x[((i >> 4) << 8) + b0 + (i & 15)];
    // pl[v*256 + c] = proj[v][wg_n0 + c]
    for (int i = tid; i < NVOC * 256; i += 1024)
        pl[i] = proj[(i >> 8) * HDIM + wg_n0 + (i & 255)];

    // B fragments: wave's K=1024 x 16-col slice of W_hh, resident in regs
    short8 bfr[32];
    const short8* wp = (const short8*)Wf;
    #pragma unroll
    for (int kk = 0; kk < 32; ++kk)
        bfr[kk] = wp[((nt << 5) + kk) * 64 + lane];

    __syncthreads();

    const int sw = (row & 7) << 4;   // XOR swizzle (bank-conflict fix)
    const int abase = row << 11;
    const int klb = kl << 4;
    unsigned int* flag = flags + g;

    for (int s = 0; s < S_LEN; ++s) {
        f32x4 acc0 = {0.f, 0.f, 0.f, 0.f};
        f32x4 acc1 = acc0, acc2 = acc0, acc3 = acc0;
        if (s > 0) {
            // wait: all 4 wgs of this group completed step s-1 (counter >= 4s)
            if (tid == 0) {
                while (__hip_atomic_load(flag, __ATOMIC_ACQUIRE, __HIP_MEMORY_SCOPE_AGENT)
                       < (unsigned)(4 * s)) {}
            }
            __syncthreads();
            // stage prev state tile (16 rows x 2048 B), source pre-swizzled so
            // linear LDS dest + swizzled ds_read agree (both-sides involution)
            const char* src = (const char*)stbf + (((s - 1) & 1) << 19) + (g << 15);
            #pragma unroll
            for (int it = 0; it < 2; ++it) {
                int o = (it * 1024 + tid) * 16;
                int arow = o >> 11;
                int soff = (arow << 11) + ((o & 2047) ^ ((arow & 7) << 4));
                __builtin_amdgcn_global_load_lds(
                    (const __attribute__((address_space(1))) void*)(src + soff),
                    (__attribute__((address_space(3))) void*)(Abuf + it * 16384 + wave * 1024),
                    16, 0, 0);
            }
            __syncthreads();
            #pragma unroll
            for (int kk = 0; kk < 32; kk += 4) {   // 4 independent acc chains
                short8 a0 = *(const short8*)(Abuf + abase + ((((kk + 0) << 6) + klb) ^ sw));
                short8 a1 = *(const short8*)(Abuf + abase + ((((kk + 1) << 6) + klb) ^ sw));
                short8 a2 = *(const short8*)(Abuf + abase + ((((kk + 2) << 6) + klb) ^ sw));
                short8 a3 = *(const short8*)(Abuf + abase + ((((kk + 3) << 6) + klb) ^ sw));
                acc0 = __builtin_amdgcn_mfma_f32_16x16x32_bf16(a0, bfr[kk + 0], acc0, 0, 0, 0);
                acc1 = __builtin_amdgcn_mfma_f32_16x16x32_bf16(a1, bfr[kk + 1], acc1, 0, 0, 0);
                acc2 = __builtin_amdgcn_mfma_f32_16x16x32_bf16(a2, bfr[kk + 2], acc2, 0, 0, 0);
                acc3 = __builtin_amdgcn_mfma_f32_16x16x32_bf16(a3, bfr[kk + 3], acc3, 0, 0, 0);
            }
        }
        f32x4 accs = acc0 + acc1 + acc2 + acc3;
        #pragma unroll
        for (int j = 0; j < 4; ++j) {
            int r = (kl << 2) + j;                 // D row = batch-local row
            int xv = xl[(s << 4) + r];
            float p = pl[(xv << 8) + (wave << 4) + row];  // col = wg_n0+wave*16+row
            float z = accs[j] + p;
            z = fminf(15.f, fmaxf(-15.f, z));
            float e = exp2f(z * 2.885390082f);     // e^(2z)
            float th = (e - 1.f) / (e + 1.f);      // tanh(z)
            if (s < S_LEN - 1) {
                stbf[((s & 1) << 18) + ((b0 + r) << 10) + n0 + row] = f2bf(th);
            } else {
                stf[((b0 + r) << 10) + n0 + row] = th;
            }
        }
        if (s < S_LEN - 1) {
            __syncthreads();  // drains all waves' stores (vmcnt0 before barrier)
            if (tid == 0)
                __hip_atomic_fetch_add(flag, 1u,
                                       __ATOMIC_RELEASE, __HIP_MEMORY_SCOPE_AGENT);
        }
    }
}

// out[b][c] = state_f32[b] @ W_ph[:,c] + b_p[c]
__global__ void outproj_k(const float* __restrict__ stf, const float* __restrict__ W_ph,
                          const float* __restrict__ b_p, float* __restrict__ out) {
    int b = blockIdx.x, t = threadIdx.x;
    float acc[10];
    #pragma unroll
    for (int c = 0; c < 10; ++c) acc[c] = 0.f;
    for (int h = t; h < HDIM; h += 256) {
        float sv = stf[b * HDIM + h];
        const float* w = W_ph + h * 10;
        #pragma unroll
        for (int c = 0; c < 10; ++c) acc[c] += sv * w[c];
    }
    __shared__ float red[256][10];
    #pragma unroll
    for (int c = 0; c < 10; ++c) red[t][c] = acc[c];
    __syncthreads();
    for (int off = 128; off > 0; off >>= 1) {
        if (t < off) {
            #pragma unroll
            for (int c = 0; c < 10; ++c) red[t][c] += red[t + off][c];
        }
        __syncthreads();
    }
    if (t < 10) out[b * 10 + t] = red[0][t] + b_p[t];
}

extern "C" void kernel_launch(void* const* d_in, const int* in_sizes, int n_in,
                              void* d_out, int out_size, void* d_ws, size_t ws_size,
                              hipStream_t stream) {
    const int*   x    = (const int*)d_in[0];
    const float* emb  = (const float*)d_in[1];
    const float* W_hx = (const float*)d_in[2];
    const float* W_hh = (const float*)d_in[3];
    const float* W_ph = (const float*)d_in[4];
    const float* b_h  = (const float*)d_in[5];
    const float* b_p  = (const float*)d_in[6];

    char* ws = (char*)d_ws;
    unsigned short* Wf    = (unsigned short*)(ws + OFF_WF);
    float*          proj  = (float*)(ws + OFF_PROJ);
    unsigned short* stbf  = (unsigned short*)(ws + OFF_STBF);
    float*          stf   = (float*)(ws + OFF_STF);
    unsigned int*   flags = (unsigned int*)(ws + OFF_FLAGS);

    zero_flags_k<<<1, 64, 0, stream>>>(flags);
    proj_k<<<40, 256, 0, stream>>>(emb, W_hx, b_h, proj);
    packw_k<<<512, 256, 0, stream>>>(W_hh, Wf);
    rnn_steps_k<<<64, 1024, 0, stream>>>(x, Wf, proj, stbf, stf, flags);
    outproj_k<<<256, 256, 0, stream>>>(stf, W_ph, b_p, (float*)d_out);
}

// Round 5
// 3307.600 us; speedup vs baseline: 2.5109x; 1.7364x over previous
//
#include <hip/hip_runtime.h>
#include <hip/hip_bf16.h>

// VanillaRNN: S=512,B=256,E=256,H=1024,C=10, vocab=10
// R5 = R2 structure (16 groups x 16 wgs x 256 thr, W resident in 128 regs)
// with the acquire path removed:
//  - consumer poll: RELAXED agent load (no bulk L2 invalidate per poll)
//  - staging: global_load_lds aux=SC0|SC1 (17) -> read MALL directly,
//    correct under any wg->XCD mapping (producer release-RMW wrote back)
//  - producer: plain stores + __syncthreads (vmcnt drain) + RELEASE RMW

typedef __attribute__((ext_vector_type(8))) short short8;
typedef __attribute__((ext_vector_type(4))) float f32x4;

#define S_LEN 512
#define HDIM  1024
#define NVOC  10

// ws layout (bytes)
#define OFF_WF    0u          // 1024*1024 bf16 frag-packed = 2 MB
#define OFF_PROJ  2097152u    // 10*1024 f32
#define OFF_STBF  2138112u    // 2 x 256*1024 bf16 (ping-pong)
#define OFF_STF   3186688u    // 256*1024 f32
#define OFF_FLAGS 4235264u    // 16 groups * 512 steps u32 (one slot per step)

__global__ void zero_flags_k(unsigned int* flags) {
    int id = blockIdx.x * 256 + threadIdx.x;
    if (id < 16 * S_LEN) flags[id] = 0u;
}

// proj[v][h] = sum_e emb[v][e]*W_hx[e][h] + b_h[h]
__global__ void proj_k(const float* __restrict__ emb, const float* __restrict__ W_hx,
                       const float* __restrict__ b_h, float* __restrict__ proj) {
    int id = blockIdx.x * 256 + threadIdx.x;
    if (id >= NVOC * HDIM) return;
    int v = id >> 10, h = id & 1023;
    float a = b_h[h];
    #pragma unroll 8
    for (int e = 0; e < 256; ++e) a += emb[v * 256 + e] * W_hx[e * HDIM + h];
    proj[id] = a;
}

static __device__ inline unsigned short f2bf(float f) {
    unsigned u = __builtin_bit_cast(unsigned, f);
    return (unsigned short)((u + 0x7fffu + ((u >> 16) & 1u)) >> 16);
}

// pack W_hh[k][n] (f32) -> Wf frag layout: [nt(64)][kk(32)][lane(64)][8] bf16
// lane l of (nt,kk) holds W[kk*32 + (l>>4)*8 + j][nt*16 + (l&15)]
__global__ void packw_k(const float* __restrict__ W_hh, unsigned short* __restrict__ Wf) {
    int idx = blockIdx.x * 256 + threadIdx.x;   // 131072 total
    int lane = idx & 63, kk = (idx >> 6) & 31, nt = idx >> 11;
    int k0 = kk * 32 + (lane >> 4) * 8;
    int col = nt * 16 + (lane & 15);
    short8 v;
    #pragma unroll
    for (int j = 0; j < 8; ++j) v[j] = (short)f2bf(W_hh[(k0 + j) * HDIM + col]);
    *(short8*)(Wf + (size_t)idx * 8) = v;
}

__global__ __launch_bounds__(256, 1) void rnn_steps_k(
    const int* __restrict__ x, const unsigned short* __restrict__ Wf,
    const float* __restrict__ proj, unsigned short* __restrict__ stbf,
    float* __restrict__ stf, unsigned int* __restrict__ flags)
{
    const int bid = blockIdx.x;
    // keep a group's 16 wgs on one XCD (bid%8 heuristic; perf-only, not correctness)
    const int g   = ((bid & 7) << 1) | ((bid >> 3) & 1);   // 0..15 batch-group
    const int wgn = bid >> 4;                              // 0..15 col-block
    const int tid = threadIdx.x;
    const int wave = tid >> 6, lane = tid & 63;
    const int b0 = g << 4;                 // batch row base
    const int nt = (wgn << 2) + wave;      // global 16-col tile index
    const int n0 = nt << 4;                // col base (per wave)
    const int wg_n0 = wgn << 6;            // col base (per workgroup)
    const int row = lane & 15;             // A-row / D-col lane index
    const int kl  = lane >> 4;             // k-group

    __shared__ __align__(16) char Abuf[32768];     // 16 x 1024 bf16 (swizzled)
    __shared__ unsigned char xl[S_LEN * 16];       // x slice for this group
    __shared__ float pl[NVOC * 64];                // proj slice for this wg

    for (int i = tid; i < S_LEN * 16; i += 256)
        xl[i] = (unsigned char)x[((i >> 4) << 8) + b0 + (i & 15)];
    // pl[v*64 + c] = proj[v][wg_n0 + c]
    for (int i = tid; i < NVOC * 64; i += 256)
        pl[i] = proj[(i >> 6) * HDIM + wg_n0 + (i & 63)];

    // B fragments: wave's K=1024 x 16-col slice of W_hh, resident in regs
    short8 bfr[32];
    const short8* wp = (const short8*)Wf;
    #pragma unroll
    for (int kk = 0; kk < 32; ++kk)
        bfr[kk] = wp[((nt << 5) + kk) * 64 + lane];

    __syncthreads();

    const int sw = (row & 7) << 4;   // XOR swizzle (bank-conflict fix)
    const int abase = row << 11;
    const int klb = kl << 4;

    for (int s = 0; s < S_LEN; ++s) {
        f32x4 acc0 = {0.f, 0.f, 0.f, 0.f};
        f32x4 acc1 = acc0, acc2 = acc0, acc3 = acc0;
        if (s > 0) {
            if (tid == 0) {
                const unsigned int* fp = flags + (g << 9) + (s - 1);
                // RELAXED: no per-poll bulk L2 invalidate; producer's release
                // already pushed data to MALL, staging reads bypass L1+L2.
                while (__hip_atomic_load(fp, __ATOMIC_RELAXED, __HIP_MEMORY_SCOPE_AGENT) < 16u) {}
            }
            __syncthreads();
            // stage prev state tile (16 rows x 2048 B), source pre-swizzled so
            // linear LDS dest + swizzled ds_read agree; aux=17 (SC0|SC1) reads MALL
            const char* src = (const char*)stbf + (((s - 1) & 1) << 19) + (g << 15);
            #pragma unroll
            for (int it = 0; it < 8; ++it) {
                int o = (it * 256 + tid) * 16;
                int arow = o >> 11;
                int soff = (arow << 11) + ((o & 2047) ^ ((arow & 7) << 4));
                __builtin_amdgcn_global_load_lds(
                    (const __attribute__((address_space(1))) void*)(src + soff),
                    (__attribute__((address_space(3))) void*)(Abuf + it * 4096 + wave * 1024),
                    16, 0, 17);
            }
            __syncthreads();
            #pragma unroll
            for (int kk = 0; kk < 32; kk += 4) {   // 4 independent acc chains
                short8 a0 = *(const short8*)(Abuf + abase + ((((kk + 0) << 6) + klb) ^ sw));
                short8 a1 = *(const short8*)(Abuf + abase + ((((kk + 1) << 6) + klb) ^ sw));
                short8 a2 = *(const short8*)(Abuf + abase + ((((kk + 2) << 6) + klb) ^ sw));
                short8 a3 = *(const short8*)(Abuf + abase + ((((kk + 3) << 6) + klb) ^ sw));
                acc0 = __builtin_amdgcn_mfma_f32_16x16x32_bf16(a0, bfr[kk + 0], acc0, 0, 0, 0);
                acc1 = __builtin_amdgcn_mfma_f32_16x16x32_bf16(a1, bfr[kk + 1], acc1, 0, 0, 0);
                acc2 = __builtin_amdgcn_mfma_f32_16x16x32_bf16(a2, bfr[kk + 2], acc2, 0, 0, 0);
                acc3 = __builtin_amdgcn_mfma_f32_16x16x32_bf16(a3, bfr[kk + 3], acc3, 0, 0, 0);
            }
        }
        f32x4 accs = acc0 + acc1 + acc2 + acc3;
        #pragma unroll
        for (int j = 0; j < 4; ++j) {
            int r = (kl << 2) + j;                 // D row = batch-local row
            int xv = xl[(s << 4) + r];
            float p = pl[(xv << 6) + (wave << 4) + row];  // col = wg_n0+wave*16+row
            float z = accs[j] + p;
            z = fminf(15.f, fmaxf(-15.f, z));
            float e = exp2f(z * 2.885390082f);     // e^(2z)
            float th = (e - 1.f) / (e + 1.f);      // tanh(z)
            if (s < S_LEN - 1) {
                stbf[((s & 1) << 18) + ((b0 + r) << 10) + n0 + row] = f2bf(th);
            } else {
                stf[((b0 + r) << 10) + n0 + row] = th;
            }
        }
        if (s < S_LEN - 1) {
            __syncthreads();  // drains all waves' stores (vmcnt0 before barrier)
            if (tid == 0)
                __hip_atomic_fetch_add(flags + (g << 9) + s, 1u,
                                       __ATOMIC_RELEASE, __HIP_MEMORY_SCOPE_AGENT);
        }
    }
}

// out[b][c] = state_f32[b] @ W_ph[:,c] + b_p[c]
__global__ void outproj_k(const float* __restrict__ stf, const float* __restrict__ W_ph,
                          const float* __restrict__ b_p, float* __restrict__ out) {
    int b = blockIdx.x, t = threadIdx.x;
    float acc[10];
    #pragma unroll
    for (int c = 0; c < 10; ++c) acc[c] = 0.f;
    for (int h = t; h < HDIM; h += 256) {
        float sv = stf[b * HDIM + h];
        const float* w = W_ph + h * 10;
        #pragma unroll
        for (int c = 0; c < 10; ++c) acc[c] += sv * w[c];
    }
    __shared__ float red[256][10];
    #pragma unroll
    for (int c = 0; c < 10; ++c) red[t][c] = acc[c];
    __syncthreads();
    for (int off = 128; off > 0; off >>= 1) {
        if (t < off) {
            #pragma unroll
            for (int c = 0; c < 10; ++c) red[t][c] += red[t + off][c];
        }
        __syncthreads();
    }
    if (t < 10) out[b * 10 + t] = red[0][t] + b_p[t];
}

extern "C" void kernel_launch(void* const* d_in, const int* in_sizes, int n_in,
                              void* d_out, int out_size, void* d_ws, size_t ws_size,
                              hipStream_t stream) {
    const int*   x    = (const int*)d_in[0];
    const float* emb  = (const float*)d_in[1];
    const float* W_hx = (const float*)d_in[2];
    const float* W_hh = (const float*)d_in[3];
    const float* W_ph = (const float*)d_in[4];
    const float* b_h  = (const float*)d_in[5];
    const float* b_p  = (const float*)d_in[6];

    char* ws = (char*)d_ws;
    unsigned short* Wf    = (unsigned short*)(ws + OFF_WF);
    float*          proj  = (float*)(ws + OFF_PROJ);
    unsigned short* stbf  = (unsigned short*)(ws + OFF_STBF);
    float*          stf   = (float*)(ws + OFF_STF);
    unsigned int*   flags = (unsigned int*)(ws + OFF_FLAGS);

    zero_flags_k<<<32, 256, 0, stream>>>(flags);
    proj_k<<<40, 256, 0, stream>>>(emb, W_hx, b_h, proj);
    packw_k<<<512, 256, 0, stream>>>(W_hh, Wf);
    rnn_steps_k<<<256, 256, 0, stream>>>(x, Wf, proj, stbf, stf, flags);
    outproj_k<<<256, 256, 0, stream>>>(stf, W_ph, b_p, (float*)d_out);
}

// Round 6
// 1137.303 us; speedup vs baseline: 7.3025x; 2.9083x over previous
//
#include <hip/hip_runtime.h>
#include <hip/hip_bf16.h>

// VanillaRNN: S=512,B=256,E=256,H=1024,C=10, vocab=10
// R6 = R5 + XCD-detected dual protocol:
//  - each wg reads its XCD via s_getreg(HW_REG_XCC_ID); group publishes and
//    checks "all 16 wgs on my XCD" once at startup
//  - FAST (uniform group): plain stores -> shared XCD L2; syncthreads
//    (vmcnt drain) + RELAXED RMW at L2 (no wbl2); relaxed L2 poll;
//    staging aux=1 (SC0: bypass L1, hit L2)
//  - FALLBACK (cross-XCD): exact R5 protocol (RELEASE RMW w/ wbl2,
//    relaxed poll, staging aux=17 reads MALL)
// Correctness never depends on placement: both paths are correct; placement
// only selects which one runs (Guideline 16 compliant).

typedef __attribute__((ext_vector_type(8))) short short8;
typedef __attribute__((ext_vector_type(4))) float f32x4;

#define S_LEN 512
#define HDIM  1024
#define NVOC  10

// ws layout (bytes)
#define OFF_WF    0u          // 1024*1024 bf16 frag-packed = 2 MB
#define OFF_PROJ  2097152u    // 10*1024 f32
#define OFF_STBF  2138112u    // 2 x 256*1024 bf16 (ping-pong)
#define OFF_STF   3186688u    // 256*1024 f32
#define OFF_FLAGS 4235264u    // 16 groups * 512 steps u32
#define OFF_XCD   4268032u    // 16*16 u32 xcd map
#define OFF_SETUP 4269056u    // 16 u32 setup counters

__global__ void zero_flags_k(unsigned int* flags) {
    int id = blockIdx.x * 256 + threadIdx.x;
    if (id < 16 * S_LEN + 256 + 16) flags[id] = 0u;   // flags + xcdmap + setup
}

// proj[v][h] = sum_e emb[v][e]*W_hx[e][h] + b_h[h]
__global__ void proj_k(const float* __restrict__ emb, const float* __restrict__ W_hx,
                       const float* __restrict__ b_h, float* __restrict__ proj) {
    int id = blockIdx.x * 256 + threadIdx.x;
    if (id >= NVOC * HDIM) return;
    int v = id >> 10, h = id & 1023;
    float a = b_h[h];
    #pragma unroll 8
    for (int e = 0; e < 256; ++e) a += emb[v * 256 + e] * W_hx[e * HDIM + h];
    proj[id] = a;
}

static __device__ inline unsigned short f2bf(float f) {
    unsigned u = __builtin_bit_cast(unsigned, f);
    return (unsigned short)((u + 0x7fffu + ((u >> 16) & 1u)) >> 16);
}

// pack W_hh[k][n] (f32) -> Wf frag layout: [nt(64)][kk(32)][lane(64)][8] bf16
__global__ void packw_k(const float* __restrict__ W_hh, unsigned short* __restrict__ Wf) {
    int idx = blockIdx.x * 256 + threadIdx.x;   // 131072 total
    int lane = idx & 63, kk = (idx >> 6) & 31, nt = idx >> 11;
    int k0 = kk * 32 + (lane >> 4) * 8;
    int col = nt * 16 + (lane & 15);
    short8 v;
    #pragma unroll
    for (int j = 0; j < 8; ++j) v[j] = (short)f2bf(W_hh[(k0 + j) * HDIM + col]);
    *(short8*)(Wf + (size_t)idx * 8) = v;
}

__global__ __launch_bounds__(256, 1) void rnn_steps_k(
    const int* __restrict__ x, const unsigned short* __restrict__ Wf,
    const float* __restrict__ proj, unsigned short* __restrict__ stbf,
    float* __restrict__ stf, unsigned int* __restrict__ flags,
    unsigned int* __restrict__ xcdmap, unsigned int* __restrict__ setupf)
{
    const int bid = blockIdx.x;
    // bid%8 round-robin puts group g's 16 wgs on XCD g>>1 (heuristic; verified
    // at runtime below — correctness does not depend on it)
    const int g   = ((bid & 7) << 1) | ((bid >> 3) & 1);   // 0..15 batch-group
    const int wgn = bid >> 4;                              // 0..15 col-block
    const int tid = threadIdx.x;
    const int wave = tid >> 6, lane = tid & 63;
    const int b0 = g << 4;
    const int nt = (wgn << 2) + wave;      // global 16-col tile index
    const int n0 = nt << 4;                // col base (per wave)
    const int wg_n0 = wgn << 6;            // col base (per workgroup)
    const int row = lane & 15;
    const int kl  = lane >> 4;

    __shared__ __align__(16) char Abuf[32768];     // 16 x 1024 bf16 (swizzled)
    __shared__ unsigned char xl[S_LEN * 16];
    __shared__ float pl[NVOC * 64];
    __shared__ unsigned uni_sh;

    // --- XCD detection + group-uniformity check (once) ---
    unsigned xcd;
    asm("s_getreg_b32 %0, hwreg(HW_REG_XCC_ID)" : "=s"(xcd));
    if (tid == 0) {
        xcdmap[(g << 4) + wgn] = xcd;   // plain store, pushed by release RMW
        __hip_atomic_fetch_add(setupf + g, 1u, __ATOMIC_RELEASE, __HIP_MEMORY_SCOPE_AGENT);
        while (__hip_atomic_load(setupf + g, __ATOMIC_ACQUIRE, __HIP_MEMORY_SCOPE_AGENT) < 16u) {}
        unsigned u = 1u;
        for (int i = 0; i < 16; ++i) {
            unsigned v = __hip_atomic_load(xcdmap + (g << 4) + i,
                                           __ATOMIC_RELAXED, __HIP_MEMORY_SCOPE_AGENT);
            u &= (unsigned)(v == xcd);
        }
        uni_sh = u;
    }

    for (int i = tid; i < S_LEN * 16; i += 256)
        xl[i] = (unsigned char)x[((i >> 4) << 8) + b0 + (i & 15)];
    for (int i = tid; i < NVOC * 64; i += 256)
        pl[i] = proj[(i >> 6) * HDIM + wg_n0 + (i & 63)];

    // B fragments: wave's K=1024 x 16-col slice of W_hh, resident in regs
    short8 bfr[32];
    const short8* wp = (const short8*)Wf;
    #pragma unroll
    for (int kk = 0; kk < 32; ++kk)
        bfr[kk] = wp[((nt << 5) + kk) * 64 + lane];

    __syncthreads();
    const bool uniform = (uni_sh != 0u);

    const int sw = (row & 7) << 4;   // XOR swizzle (bank-conflict fix)
    const int abase = row << 11;
    const int klb = kl << 4;

    for (int s = 0; s < S_LEN; ++s) {
        f32x4 acc0 = {0.f, 0.f, 0.f, 0.f};
        f32x4 acc1 = acc0, acc2 = acc0, acc3 = acc0;
        if (s > 0) {
            if (tid == 0) {
                const unsigned int* fp = flags + (g << 9) + (s - 1);
                // relaxed poll (atomic load bypasses L1; L2-resident in fast path)
                while (__hip_atomic_load(fp, __ATOMIC_RELAXED, __HIP_MEMORY_SCOPE_AGENT) < 16u) {}
            }
            __syncthreads();
            const char* src = (const char*)stbf + (((s - 1) & 1) << 19) + (g << 15);
            if (uniform) {
                // FAST: producers share this XCD's L2 -> SC0 only (bypass L1)
                #pragma unroll
                for (int it = 0; it < 8; ++it) {
                    int o = (it * 256 + tid) * 16;
                    int arow = o >> 11;
                    int soff = (arow << 11) + ((o & 2047) ^ ((arow & 7) << 4));
                    __builtin_amdgcn_global_load_lds(
                        (const __attribute__((address_space(1))) void*)(src + soff),
                        (__attribute__((address_space(3))) void*)(Abuf + it * 4096 + wave * 1024),
                        16, 0, 1);
                }
            } else {
                // FALLBACK: cross-XCD -> read MALL (SC0|SC1), R5-proven
                #pragma unroll
                for (int it = 0; it < 8; ++it) {
                    int o = (it * 256 + tid) * 16;
                    int arow = o >> 11;
                    int soff = (arow << 11) + ((o & 2047) ^ ((arow & 7) << 4));
                    __builtin_amdgcn_global_load_lds(
                        (const __attribute__((address_space(1))) void*)(src + soff),
                        (__attribute__((address_space(3))) void*)(Abuf + it * 4096 + wave * 1024),
                        16, 0, 17);
                }
            }
            __syncthreads();
            #pragma unroll
            for (int kk = 0; kk < 32; kk += 4) {   // 4 independent acc chains
                short8 a0 = *(const short8*)(Abuf + abase + ((((kk + 0) << 6) + klb) ^ sw));
                short8 a1 = *(const short8*)(Abuf + abase + ((((kk + 1) << 6) + klb) ^ sw));
                short8 a2 = *(const short8*)(Abuf + abase + ((((kk + 2) << 6) + klb) ^ sw));
                short8 a3 = *(const short8*)(Abuf + abase + ((((kk + 3) << 6) + klb) ^ sw));
                acc0 = __builtin_amdgcn_mfma_f32_16x16x32_bf16(a0, bfr[kk + 0], acc0, 0, 0, 0);
                acc1 = __builtin_amdgcn_mfma_f32_16x16x32_bf16(a1, bfr[kk + 1], acc1, 0, 0, 0);
                acc2 = __builtin_amdgcn_mfma_f32_16x16x32_bf16(a2, bfr[kk + 2], acc2, 0, 0, 0);
                acc3 = __builtin_amdgcn_mfma_f32_16x16x32_bf16(a3, bfr[kk + 3], acc3, 0, 0, 0);
            }
        }
        f32x4 accs = acc0 + acc1 + acc2 + acc3;
        #pragma unroll
        for (int j = 0; j < 4; ++j) {
            int r = (kl << 2) + j;
            int xv = xl[(s << 4) + r];
            float p = pl[(xv << 6) + (wave << 4) + row];
            float z = accs[j] + p;
            z = fminf(15.f, fmaxf(-15.f, z));
            float e = exp2f(z * 2.885390082f);
            float th = (e - 1.f) / (e + 1.f);
            if (s < S_LEN - 1) {
                stbf[((s & 1) << 18) + ((b0 + r) << 10) + n0 + row] = f2bf(th);
            } else {
                stf[((b0 + r) << 10) + n0 + row] = th;
            }
        }
        if (s < S_LEN - 1) {
            __syncthreads();  // drains stores (vmcnt0): L2-acked (fast) / pre-release (fb)
            if (tid == 0) {
                if (uniform) {
                    // same-XCD: relaxed RMW executes at shared L2, no wbl2
                    __hip_atomic_fetch_add(flags + (g << 9) + s, 1u,
                                           __ATOMIC_RELAXED, __HIP_MEMORY_SCOPE_AGENT);
                } else {
                    // cross-XCD: release pushes state to MALL first
                    __hip_atomic_fetch_add(flags + (g << 9) + s, 1u,
                                           __ATOMIC_RELEASE, __HIP_MEMORY_SCOPE_AGENT);
                }
            }
        }
    }
}

// out[b][c] = state_f32[b] @ W_ph[:,c] + b_p[c]
__global__ void outproj_k(const float* __restrict__ stf, const float* __restrict__ W_ph,
                          const float* __restrict__ b_p, float* __restrict__ out) {
    int b = blockIdx.x, t = threadIdx.x;
    float acc[10];
    #pragma unroll
    for (int c = 0; c < 10; ++c) acc[c] = 0.f;
    for (int h = t; h < HDIM; h += 256) {
        float sv = stf[b * HDIM + h];
        const float* w = W_ph + h * 10;
        #pragma unroll
        for (int c = 0; c < 10; ++c) acc[c] += sv * w[c];
    }
    __shared__ float red[256][10];
    #pragma unroll
    for (int c = 0; c < 10; ++c) red[t][c] = acc[c];
    __syncthreads();
    for (int off = 128; off > 0; off >>= 1) {
        if (t < off) {
            #pragma unroll
            for (int c = 0; c < 10; ++c) red[t][c] += red[t + off][c];
        }
        __syncthreads();
    }
    if (t < 10) out[b * 10 + t] = red[0][t] + b_p[t];
}

extern "C" void kernel_launch(void* const* d_in, const int* in_sizes, int n_in,
                              void* d_out, int out_size, void* d_ws, size_t ws_size,
                              hipStream_t stream) {
    const int*   x    = (const int*)d_in[0];
    const float* emb  = (const float*)d_in[1];
    const float* W_hx = (const float*)d_in[2];
    const float* W_hh = (const float*)d_in[3];
    const float* W_ph = (const float*)d_in[4];
    const float* b_h  = (const float*)d_in[5];
    const float* b_p  = (const float*)d_in[6];

    char* ws = (char*)d_ws;
    unsigned short* Wf     = (unsigned short*)(ws + OFF_WF);
    float*          proj   = (float*)(ws + OFF_PROJ);
    unsigned short* stbf   = (unsigned short*)(ws + OFF_STBF);
    float*          stf    = (float*)(ws + OFF_STF);
    unsigned int*   flags  = (unsigned int*)(ws + OFF_FLAGS);
    unsigned int*   xcdmap = (unsigned int*)(ws + OFF_XCD);
    unsigned int*   setupf = (unsigned int*)(ws + OFF_SETUP);

    zero_flags_k<<<34, 256, 0, stream>>>(flags);
    proj_k<<<40, 256, 0, stream>>>(emb, W_hx, b_h, proj);
    packw_k<<<512, 256, 0, stream>>>(W_hh, Wf);
    rnn_steps_k<<<256, 256, 0, stream>>>(x, Wf, proj, stbf, stf, flags, xcdmap, setupf);
    outproj_k<<<256, 256, 0, stream>>>(stf, W_ph, b_p, (float*)d_out);
}